// Round 2
// baseline (2096.473 us; speedup 1.0000x reference)
//
#include <hip/hip_runtime.h>
#include <math.h>

namespace {

constexpr int B   = 8;
constexpr int C   = 256;
constexpr int NH  = 4;
constexpr int HD  = 64;
constexpr int NWIN = 400;   // 20x20 windows, same at every level
constexpr int NT  = 35;     // 25 + 9 + 1 tokens per window
constexpr int QKVN = 768;
constexpr int RPB = NWIN * NT;  // 14,000 token-rows per (b)

// per-batch float counts
constexpr size_t QKV_PB  = (size_t)8400 * QKVN;      // 6,451,200
constexpr size_t OATT_PB = (size_t)NWIN * NT * C;    // 3,584,000
constexpr size_t PB_F    = QKV_PB + OATT_PB;         // 10,035,200

// ---------------- pos table ----------------
__device__ inline void token_coord(int j, double& cy, double& cx) {
  if (j < 25)      { int ty = j / 5,  tx = j % 5;  cy = (double)(ty - 2); cx = (double)(tx - 2); }
  else if (j < 34) { int t = j - 25; int ty = t / 3, tx = t % 3;
                     cy = (double)(ty - 1) * (5.0 / 3.0); cx = (double)(tx - 1) * (5.0 / 3.0); }
  else             { cy = 0.0; cx = 0.0; }
}

__global__ void pos_kernel(const float* __restrict__ rpb, const float* __restrict__ ab,
                           float* __restrict__ pos) {
  int p = blockIdx.x * blockDim.x + threadIdx.x;
  if (p >= NH * NT * NT) return;
  int j = p % NT, i = (p / NT) % NT, h = p / (NT * NT);
  double cyi, cxi, cyj, cxj;
  token_coord(i, cyi, cxi);
  token_coord(j, cyj, cxj);
  float fidx = (float)(((cyi - cyj) + 4.0) * 9.0 + ((cxi - cxj) + 4.0));
  int fl = min(max((int)floorf(fidx), 0), 80);
  int ce = min(max((int)ceilf(fidx), 0), 80);
  float w = fidx - (float)fl;
  float pv = (1.0f - w) * rpb[fl * NH + h] + w * rpb[ce * NH + h];
  int li = (i < 25) ? 0 : ((i < 34) ? 1 : 2);
  pos[p] = pv + ab[li * NH + h];
}

// ---------------- per-pixel QKV GEMM:  Y[m, 768] = X[b(m), :, pix(m)]^T @ Wq ----------------
// X: group base, (g, C, HW) channel-first.  Mg = g*HW rows.
__global__ __launch_bounds__(256) void qkv_gemm(const float* __restrict__ X,
                                                const float* __restrict__ W,
                                                float* __restrict__ Y, int HW, int Mg) {
  __shared__ float As[16][65];
  __shared__ float Bs[16][65];
  const int tid = threadIdx.x;
  const int m0 = blockIdx.x * 64;
  const int n0 = blockIdx.y * 64;

  const int lr = tid & 63;          // row/col within tile for loads
  const int lk = tid >> 6;          // 0..3
  const int ty = (tid >> 4) * 4;    // 0..60
  const int tx = (tid & 15) * 4;

  // per-lane row decode (tiles may cross batch boundaries when HW % 64 != 0)
  const int m  = m0 + lr;
  const int mc = min(m, Mg - 1);
  const int bb = mc / HW;
  const int pix = mc - bb * HW;
  const bool mval = (m < Mg);
  const float* Xp = X + (size_t)bb * C * HW + pix;

  float acc[4][4] = {};
  for (int k0 = 0; k0 < C; k0 += 16) {
#pragma unroll
    for (int u = 0; u < 4; ++u) {
      int kk = lk + u * 4;
      As[kk][lr] = mval ? Xp[(size_t)(k0 + kk) * HW] : 0.f;
      Bs[kk][lr] = W[(size_t)(k0 + kk) * QKVN + n0 + lr];
    }
    __syncthreads();
#pragma unroll
    for (int kk = 0; kk < 16; ++kk) {
      float a[4], bbv[4];
#pragma unroll
      for (int i = 0; i < 4; ++i) a[i] = As[kk][ty + i];
#pragma unroll
      for (int j = 0; j < 4; ++j) bbv[j] = Bs[kk][tx + j];
#pragma unroll
      for (int i = 0; i < 4; ++i)
#pragma unroll
        for (int j = 0; j < 4; ++j) acc[i][j] += a[i] * bbv[j];
    }
    __syncthreads();
  }
#pragma unroll
  for (int i = 0; i < 4; ++i) {
    int row = m0 + ty + i;
    if (row < Mg) {
      float4 v = make_float4(acc[i][0], acc[i][1], acc[i][2], acc[i][3]);
      *(float4*)&Y[(size_t)row * QKVN + n0 + tx] = v;
    }
  }
}

// ---------------- attention: one wave per (b_local, h, w) ----------------
__global__ __launch_bounds__(64) void attn_kernel(const float* __restrict__ qkv0,
                                                  const float* __restrict__ qkv1,
                                                  const float* __restrict__ qkv2,
                                                  const float* __restrict__ pos,
                                                  float* __restrict__ O) {
  const int blk = blockIdx.x;               // ((b*NH + h)*NWIN + w), b group-local
  const int w = blk % NWIN;
  const int h = (blk / NWIN) % NH;
  const int b = blk / (NWIN * NH);
  const int wy = w / 20, wx = w % 20;
  const int lane = threadIdx.x;             // 0..63 = d

  __shared__ float qs[NT][65];
  __shared__ float ks[NT][65];
  __shared__ float vs[NT][65];
  __shared__ float sc[NT][36];

  // gather q/k/v (zeros for padding tokens)
  for (int j = 0; j < NT; ++j) {
    int k_, s_, p_, Hl, t;
    const float* base;
    if (j < 25)      { k_ = 5; s_ = 4; p_ = 2; Hl = 80; t = j;      base = qkv0; }
    else if (j < 34) { k_ = 3; s_ = 2; p_ = 1; Hl = 40; t = j - 25; base = qkv1; }
    else             { k_ = 1; s_ = 1; p_ = 0; Hl = 20; t = 0;      base = qkv2; }
    int tyy = t / k_, txx = t % k_;
    int y = wy * s_ + tyy - p_;
    int x = wx * s_ + txx - p_;
    float qv = 0.f, kv = 0.f, vv = 0.f;
    if ((unsigned)y < (unsigned)Hl && (unsigned)x < (unsigned)Hl) {
      size_t rb = ((size_t)b * Hl * Hl + (size_t)y * Hl + x) * QKVN + h * HD + lane;
      qv = base[rb];
      kv = base[rb + 256];
      vv = base[rb + 512];
    }
    qs[j][lane] = qv; ks[j][lane] = kv; vs[j][lane] = vv;
  }
  __syncthreads();

  // l2 normalize q, k per token
  for (int j = 0; j < NT; ++j) {
    float qv = qs[j][lane];
    float kv = ks[j][lane];
    float sq = qv * qv, sk = kv * kv;
#pragma unroll
    for (int off = 32; off; off >>= 1) { sq += __shfl_xor(sq, off); sk += __shfl_xor(sk, off); }
    qs[j][lane] = qv / fmaxf(sqrtf(sq), 1e-12f);
    ks[j][lane] = kv / fmaxf(sqrtf(sk), 1e-12f);
  }
  __syncthreads();

  // scores
  for (int p = lane; p < NT * NT; p += 64) {
    int i = p / NT, j = p % NT;
    float acc = 0.f;
#pragma unroll
    for (int d = 0; d < HD; ++d) acc += qs[i][d] * ks[j][d];
    sc[i][j] = acc + pos[(h * NT + i) * NT + j];
  }
  __syncthreads();

  // softmax over j
  for (int i = 0; i < NT; ++i) {
    float val = (lane < NT) ? sc[i][lane] : -INFINITY;
    float m = val;
#pragma unroll
    for (int off = 32; off; off >>= 1) m = fmaxf(m, __shfl_xor(m, off));
    float e = (lane < NT) ? expf(val - m) : 0.f;
    float s = e;
#pragma unroll
    for (int off = 32; off; off >>= 1) s += __shfl_xor(s, off);
    if (lane < NT) sc[i][lane] = e / s;
  }
  __syncthreads();

  // PV + store  O[(b*NWIN+w)*NT + i][h*64 + d]
  for (int i = 0; i < NT; ++i) {
    float acc = 0.f;
#pragma unroll
    for (int j = 0; j < NT; ++j) acc += sc[i][j] * vs[j][lane];
    O[((size_t)(b * NWIN + w) * NT + i) * C + h * HD + lane] = acc;
  }
}

// ---------------- proj GEMM + bias, transposed store Yt[(b*256+c)*14000 + w*35+j] ----------------
__global__ __launch_bounds__(256) void proj_gemm(const float* __restrict__ A,   // (Mg, 256)
                                                 const float* __restrict__ W,   // (256, 256)
                                                 const float* __restrict__ bias,
                                                 float* __restrict__ Yt, int Mg) {
  __shared__ float As[16][65];
  __shared__ float Bs[16][65];
  __shared__ float Cs[64][65];
  const int tid = threadIdx.x;
  const int m0 = blockIdx.x * 64;
  const int n0 = blockIdx.y * 64;
  const int ai = tid >> 2;          // row 0..63
  const int ak4 = tid & 3;          // float4 index 0..3
  const int lr = tid & 63;
  const int lk = tid >> 6;
  const int ty = (tid >> 4) * 4;
  const int tx = (tid & 15) * 4;

  const int arow = min(m0 + ai, Mg - 1);

  float acc[4][4] = {};
  for (int k0 = 0; k0 < C; k0 += 16) {
    float4 av = *(const float4*)&A[(size_t)arow * C + k0 + ak4 * 4];
    As[ak4 * 4 + 0][ai] = av.x;
    As[ak4 * 4 + 1][ai] = av.y;
    As[ak4 * 4 + 2][ai] = av.z;
    As[ak4 * 4 + 3][ai] = av.w;
#pragma unroll
    for (int u = 0; u < 4; ++u) {
      int kk = lk + u * 4;
      Bs[kk][lr] = W[(size_t)(k0 + kk) * C + n0 + lr];
    }
    __syncthreads();
#pragma unroll
    for (int kk = 0; kk < 16; ++kk) {
      float a[4], bbv[4];
#pragma unroll
      for (int i = 0; i < 4; ++i) a[i] = As[kk][ty + i];
#pragma unroll
      for (int j = 0; j < 4; ++j) bbv[j] = Bs[kk][tx + j];
#pragma unroll
      for (int i = 0; i < 4; ++i)
#pragma unroll
        for (int j = 0; j < 4; ++j) acc[i][j] += a[i] * bbv[j];
    }
    __syncthreads();
  }
  // stage with bias, then transposed coalesced store
#pragma unroll
  for (int i = 0; i < 4; ++i)
#pragma unroll
    for (int j = 0; j < 4; ++j) Cs[ty + i][tx + j] = acc[i][j] + bias[n0 + tx + j];
  __syncthreads();
#pragma unroll
  for (int pass = 0; pass < 16; ++pass) {
    int cl = pass * 4 + (tid >> 6);
    int ml = tid & 63;
    int m = m0 + ml;
    if (m < Mg) {
      int bb = m / RPB;
      int r = m - bb * RPB;
      Yt[((size_t)bb * C + n0 + cl) * RPB + r] = Cs[ml][cl];
    }
  }
}

// ---------------- fold (gather form), group-local ----------------
__global__ __launch_bounds__(256) void fold_kernel(const float* __restrict__ Yt,
                                                   float* __restrict__ out,
                                                   int k_, int s_, int p_, int H_,
                                                   int toff, int total) {
  int idx = blockIdx.x * 256 + threadIdx.x;
  if (idx >= total) return;
  int x = idx % H_;
  int y = (idx / H_) % H_;
  int c = (idx / (H_ * H_)) % C;
  int b = idx / (C * H_ * H_);
  int py = y + p_, px = x + p_;
  int ay = py - k_ + 1;
  int wy_lo = ay <= 0 ? 0 : (ay + s_ - 1) / s_;
  int wy_hi = min(19, py / s_);
  int ax = px - k_ + 1;
  int wx_lo = ax <= 0 ? 0 : (ax + s_ - 1) / s_;
  int wx_hi = min(19, px / s_);
  const float* base = Yt + ((size_t)b * C + c) * RPB;
  float acc = 0.f;
  for (int wy = wy_lo; wy <= wy_hi; ++wy) {
    int tyy = py - wy * s_;
    for (int wx = wx_lo; wx <= wx_hi; ++wx) {
      int txx = px - wx * s_;
      acc += base[(wy * 20 + wx) * NT + toff + tyy * k_ + txx];
    }
  }
  out[idx] = acc;
}

} // namespace

extern "C" void kernel_launch(void* const* d_in, const int* in_sizes, int n_in,
                              void* d_out, int out_size, void* d_ws, size_t ws_size,
                              hipStream_t stream) {
  const float* x0    = (const float*)d_in[0];
  const float* x1    = (const float*)d_in[1];
  const float* x2    = (const float*)d_in[2];
  const float* wq0   = (const float*)d_in[3];
  const float* wq1   = (const float*)d_in[4];
  const float* wq2   = (const float*)d_in[5];
  const float* wproj = (const float*)d_in[6];
  const float* bproj = (const float*)d_in[7];
  const float* rpb   = (const float*)d_in[8];
  const float* ab    = (const float*)d_in[9];
  float* out = (float*)d_out;

  // pick largest batch-group size g in {8,4,2,1} that fits ws_size
  int g = 8;
  while (g > 1 && (4900 + (size_t)g * PB_F) * 4 > ws_size) g >>= 1;

  float* ws    = (float*)d_ws;
  float* posb  = ws;                         // 4900 floats (19,600 B, 16B-aligned end)
  float* qkv0g = ws + 4900;
  float* qkv1g = qkv0g + (size_t)g * 6400 * QKVN;
  float* qkv2g = qkv1g + (size_t)g * 1600 * QKVN;
  float* oatt  = qkv0g + (size_t)g * QKV_PB;
  float* yt    = qkv0g;                      // reuses dead qkv region after attention

  pos_kernel<<<(NH * NT * NT + 255) / 256, 256, 0, stream>>>(rpb, ab, posb);

  // per-level output offsets in d_out (levels concatenated, each (B,C,H,H))
  const size_t off1 = (size_t)B * C * 6400;
  const size_t off2 = off1 + (size_t)B * C * 1600;

  for (int b0 = 0; b0 < B; b0 += g) {
    const float* x0g = x0 + (size_t)b0 * C * 6400;
    const float* x1g = x1 + (size_t)b0 * C * 1600;
    const float* x2g = x2 + (size_t)b0 * C * 400;

    qkv_gemm<<<dim3((g * 6400 + 63) / 64, QKVN / 64), 256, 0, stream>>>(x0g, wq0, qkv0g, 6400, g * 6400);
    qkv_gemm<<<dim3((g * 1600 + 63) / 64, QKVN / 64), 256, 0, stream>>>(x1g, wq1, qkv1g, 1600, g * 1600);
    qkv_gemm<<<dim3((g *  400 + 63) / 64, QKVN / 64), 256, 0, stream>>>(x2g, wq2, qkv2g, 400, g * 400);

    attn_kernel<<<g * NH * NWIN, 64, 0, stream>>>(qkv0g, qkv1g, qkv2g, posb, oatt);

    proj_gemm<<<dim3((g * RPB + 63) / 64, C / 64), 256, 0, stream>>>(oatt, wproj, bproj, yt, g * RPB);

    const int tot0 = g * C * 6400;
    const int tot1 = g * C * 1600;
    const int tot2 = g * C * 400;
    fold_kernel<<<(tot0 + 255) / 256, 256, 0, stream>>>(yt, out + (size_t)b0 * C * 6400,        5, 4, 2, 80, 0,  tot0);
    fold_kernel<<<(tot1 + 255) / 256, 256, 0, stream>>>(yt, out + off1 + (size_t)b0 * C * 1600, 3, 2, 1, 40, 25, tot1);
    fold_kernel<<<(tot2 + 255) / 256, 256, 0, stream>>>(yt, out + off2 + (size_t)b0 * C * 400,  1, 1, 0, 20, 34, tot2);
  }
}

// Round 3
// 1061.459 us; speedup vs baseline: 1.9751x; 1.9751x over previous
//
#include <hip/hip_runtime.h>
#include <math.h>

namespace {

typedef _Float16 half8v __attribute__((ext_vector_type(8)));
typedef _Float16 half4v __attribute__((ext_vector_type(4)));
typedef float    floatx4 __attribute__((ext_vector_type(4)));

constexpr int B   = 8;
constexpr int C   = 256;
constexpr int NH  = 4;
constexpr int HD  = 64;
constexpr int NWIN = 400;   // 20x20 windows per level
constexpr int NT  = 35;     // 25 + 9 + 1 tokens per window
constexpr int QKVN = 768;
constexpr int RPB = NWIN * NT;  // 14,000 token-rows per batch

// per-batch float counts for workspace
constexpr size_t QKV_PB  = (size_t)8400 * QKVN;      // 6,451,200
constexpr size_t OATT_PB = (size_t)NWIN * NT * C;    // 3,584,000
constexpr size_t PB_F    = QKV_PB + OATT_PB;         // 10,035,200

__device__ inline unsigned pack2(float a, float b) {
  union { _Float16 h[2]; unsigned u; } x;
  x.h[0] = (_Float16)a; x.h[1] = (_Float16)b;
  return x.u;
}

// ---------------- pos table ----------------
__device__ inline void token_coord(int j, double& cy, double& cx) {
  if (j < 25)      { int ty = j / 5,  tx = j % 5;  cy = (double)(ty - 2); cx = (double)(tx - 2); }
  else if (j < 34) { int t = j - 25; int ty = t / 3, tx = t % 3;
                     cy = (double)(ty - 1) * (5.0 / 3.0); cx = (double)(tx - 1) * (5.0 / 3.0); }
  else             { cy = 0.0; cx = 0.0; }
}

__global__ void pos_kernel(const float* __restrict__ rpb, const float* __restrict__ ab,
                           float* __restrict__ pos) {
  int p = blockIdx.x * blockDim.x + threadIdx.x;
  if (p >= NH * NT * NT) return;
  int j = p % NT, i = (p / NT) % NT, h = p / (NT * NT);
  double cyi, cxi, cyj, cxj;
  token_coord(i, cyi, cxi);
  token_coord(j, cyj, cxj);
  float fidx = (float)(((cyi - cyj) + 4.0) * 9.0 + ((cxi - cxj) + 4.0));
  int fl = min(max((int)floorf(fidx), 0), 80);
  int ce = min(max((int)ceilf(fidx), 0), 80);
  float w = fidx - (float)fl;
  float pv = (1.0f - w) * rpb[fl * NH + h] + w * rpb[ce * NH + h];
  int li = (i < 25) ? 0 : ((i < 34) ? 1 : 2);
  pos[p] = pv + ab[li * NH + h];
}

// ---------------- QKV GEMM (f16 MFMA): Y[m, Nld] = X[b(m), :, pix(m)]^T @ W ----------------
// X column-major in m (contiguous pixels), A[m][k] = X[b, k, pix].
// Epilogue: L2-normalize each output row over this 64-wide tile when n0 < normN (q,k sections).
__global__ __launch_bounds__(256) void qkv_gemm(const float* __restrict__ X,
                                                const float* __restrict__ W,
                                                float* __restrict__ Y,
                                                int HW, int Mg, int Nld, int normN) {
  __shared__ _Float16 As[128][40];   // row 80B, 16B-aligned frag reads
  __shared__ _Float16 Bs[64][40];
  const int tid  = threadIdx.x;
  const int m0   = blockIdx.x * 128;
  const int n0   = blockIdx.y * 64;
  const int w    = tid >> 6;
  const int lane = tid & 63;
  const int quad = lane >> 4;
  const int mn   = lane & 15;

  floatx4 acc[2][4] = {};
  for (int k0 = 0; k0 < C; k0 += 32) {
    // stage A: transpose (column-major global -> row-major LDS), f16x2 packed writes
#pragma unroll
    for (int u = 0; u < 2; ++u) {
      int unit = u * 256 + tid;        // 512 units: 32 m-quads x 16 k-pairs
      int mq = unit & 31, kp = unit >> 5;
      int mb = 4 * mq;
      int gm = m0 + mb;
      if (gm + 3 < Mg) {
        int bb = gm / HW; int pix = gm - bb * HW;
        const float* xp = X + ((size_t)bb * C + (k0 + 2 * kp)) * HW + pix;
        floatx4 va = *(const floatx4*)xp;
        floatx4 vb = *(const floatx4*)(xp + HW);
#pragma unroll
        for (int i = 0; i < 4; ++i) *(unsigned*)&As[mb + i][2 * kp] = pack2(va[i], vb[i]);
      } else {
#pragma unroll
        for (int i = 0; i < 4; ++i) {
          int g = min(gm + i, Mg - 1);
          int bb = g / HW; int pix = g - bb * HW;
          const float* xp = X + ((size_t)bb * C + (k0 + 2 * kp)) * HW + pix;
          *(unsigned*)&As[mb + i][2 * kp] = pack2(xp[0], xp[HW]);
        }
      }
    }
    // stage B: W row-major (K x Nld)
    {
      int nq = tid & 15, kp = tid >> 4;
      const float* wp = W + (size_t)(k0 + 2 * kp) * Nld + n0 + 4 * nq;
      floatx4 va = *(const floatx4*)wp;
      floatx4 vb = *(const floatx4*)(wp + Nld);
#pragma unroll
      for (int i = 0; i < 4; ++i) *(unsigned*)&Bs[4 * nq + i][2 * kp] = pack2(va[i], vb[i]);
    }
    __syncthreads();
    half8v a0 = *(const half8v*)&As[w * 32 + mn][quad * 8];
    half8v a1 = *(const half8v*)&As[w * 32 + 16 + mn][quad * 8];
#pragma unroll
    for (int ni = 0; ni < 4; ++ni) {
      half8v bf = *(const half8v*)&Bs[ni * 16 + mn][quad * 8];
      acc[0][ni] = __builtin_amdgcn_mfma_f32_16x16x32_f16(a0, bf, acc[0][ni], 0, 0, 0);
      acc[1][ni] = __builtin_amdgcn_mfma_f32_16x16x32_f16(a1, bf, acc[1][ni], 0, 0, 0);
    }
    __syncthreads();
  }

  // epilogue: per-row L2 norm over the 64 cols of this tile (q,k head sections only)
  const bool do_norm = (n0 < normN);
#pragma unroll
  for (int mi = 0; mi < 2; ++mi) {
#pragma unroll
    for (int r = 0; r < 4; ++r) {
      float ss = 0.f;
#pragma unroll
      for (int ni = 0; ni < 4; ++ni) { float vv = acc[mi][ni][r]; ss += vv * vv; }
      ss += __shfl_xor(ss, 1);
      ss += __shfl_xor(ss, 2);
      ss += __shfl_xor(ss, 4);
      ss += __shfl_xor(ss, 8);
      float scale = do_norm ? (1.f / fmaxf(sqrtf(ss), 1e-12f)) : 1.f;
      int row = m0 + w * 32 + mi * 16 + quad * 4 + r;
      if (row < Mg) {
#pragma unroll
        for (int ni = 0; ni < 4; ++ni)
          Y[(size_t)row * Nld + n0 + ni * 16 + mn] = acc[mi][ni][r] * scale;
      }
    }
  }
}

// ---------------- attention: one wave per (b_local, h, w), pre-normalized q,k ----------------
__global__ __launch_bounds__(64) void attn_kernel(const float* __restrict__ qkv0,
                                                  const float* __restrict__ qkv1,
                                                  const float* __restrict__ qkv2,
                                                  const float* __restrict__ pos,
                                                  float* __restrict__ O) {
  const int blk = blockIdx.x;               // ((b*NH + h)*NWIN + w)
  const int w = blk % NWIN;
  const int h = (blk / NWIN) % NH;
  const int b = blk / (NWIN * NH);
  const int wy = w / 20, wx = w % 20;
  const int lane = threadIdx.x;             // 0..63 = d

  __shared__ float qs[NT][68];
  __shared__ float ks[NT][68];
  __shared__ float sc[NT][36];

  float vreg[36];
  vreg[35] = 0.f;

  // gather q/k (normalized) to LDS, v to registers (zeros for padding tokens)
  for (int j = 0; j < NT; ++j) {
    int k_, s_, p_, Hl, t;
    const float* base;
    if (j < 25)      { k_ = 5; s_ = 4; p_ = 2; Hl = 80; t = j;      base = qkv0; }
    else if (j < 34) { k_ = 3; s_ = 2; p_ = 1; Hl = 40; t = j - 25; base = qkv1; }
    else             { k_ = 1; s_ = 1; p_ = 0; Hl = 20; t = 0;      base = qkv2; }
    int tyy = t / k_, txx = t % k_;
    int y = wy * s_ + tyy - p_;
    int x = wx * s_ + txx - p_;
    float qv = 0.f, kv = 0.f, vv = 0.f;
    if ((unsigned)y < (unsigned)Hl && (unsigned)x < (unsigned)Hl) {
      size_t rb = ((size_t)b * Hl * Hl + (size_t)y * Hl + x) * QKVN + h * HD + lane;
      qv = base[rb];
      kv = base[rb + 256];
      vv = base[rb + 512];
    }
    qs[j][lane] = qv; ks[j][lane] = kv; vreg[j] = vv;
  }
  __syncthreads();

  // scores (float4 LDS reads; q-row is broadcast across lanes sharing i)
  for (int p = lane; p < NT * NT; p += 64) {
    int i = p / NT, j = p - i * NT;
    floatx4 a4 = {0.f, 0.f, 0.f, 0.f};
#pragma unroll
    for (int d = 0; d < HD; d += 4) {
      floatx4 qv = *(const floatx4*)&qs[i][d];
      floatx4 kv = *(const floatx4*)&ks[j][d];
      a4 += qv * kv;
    }
    sc[i][j] = a4[0] + a4[1] + a4[2] + a4[3] + pos[(h * NT + i) * NT + j];
  }
  __syncthreads();

  // softmax over j (writes sc[i][35] = 0 so PV can use float4)
  for (int i = 0; i < NT; ++i) {
    float val = (lane < NT) ? sc[i][lane] : -INFINITY;
    float m = val;
#pragma unroll
    for (int off = 32; off; off >>= 1) m = fmaxf(m, __shfl_xor(m, off));
    float e = (lane < NT) ? expf(val - m) : 0.f;
    float s = e;
#pragma unroll
    for (int off = 32; off; off >>= 1) s += __shfl_xor(s, off);
    if (lane < 36) sc[i][lane] = (lane < NT) ? (e / s) : 0.f;
  }
  __syncthreads();

  // PV with v in registers; sc reads are same-address broadcasts (conflict-free)
  for (int i = 0; i < NT; ++i) {
    float acc = 0.f;
#pragma unroll
    for (int j4 = 0; j4 < 9; ++j4) {
      floatx4 p4 = *(const floatx4*)&sc[i][4 * j4];
      acc += p4[0] * vreg[4 * j4] + p4[1] * vreg[4 * j4 + 1]
           + p4[2] * vreg[4 * j4 + 2] + p4[3] * vreg[4 * j4 + 3];
    }
    O[((size_t)(b * NWIN + w) * NT + i) * C + h * HD + lane] = acc;
  }
}

// ---------------- proj GEMM (f16 MFMA) + bias, transposed store Yt[(b*C+c)*RPB + w*35+j] ----------------
__global__ __launch_bounds__(256) void proj_gemm(const float* __restrict__ A,   // (Mg, 256) row-major
                                                 const float* __restrict__ W,   // (256, 256) row-major
                                                 const float* __restrict__ bias,
                                                 float* __restrict__ Yt, int Mg) {
  __shared__ __align__(16) char smem[128 * 69 * 4];   // max(As+Bs = 15360, Cs = 35328)
  _Float16 (*As)[40] = (_Float16(*)[40])smem;
  _Float16 (*Bs)[40] = (_Float16(*)[40])(smem + 128 * 40 * 2);
  float    (*Cs)[69] = (float(*)[69])smem;

  const int tid  = threadIdx.x;
  const int m0   = blockIdx.x * 128;
  const int n0   = blockIdx.y * 64;
  const int w    = tid >> 6;
  const int lane = tid & 63;
  const int quad = lane >> 4;
  const int mn   = lane & 15;

  floatx4 acc[2][4] = {};
  for (int k0 = 0; k0 < C; k0 += 32) {
    // stage A (row-major): float4 load along k, half4 LDS write
#pragma unroll
    for (int u = 0; u < 4; ++u) {
      int e = u * 256 + tid;           // 1024 units: 128 m x 8 k-quads
      int m = e >> 3, k4 = e & 7;
      int row = min(m0 + m, Mg - 1);
      floatx4 va = *(const floatx4*)&A[(size_t)row * C + k0 + 4 * k4];
      half4v hv;
#pragma unroll
      for (int i = 0; i < 4; ++i) hv[i] = (_Float16)va[i];
      *(half4v*)&As[m][4 * k4] = hv;
    }
    // stage B
    {
      int nq = tid & 15, kp = tid >> 4;
      const float* wp = W + (size_t)(k0 + 2 * kp) * C + n0 + 4 * nq;
      floatx4 va = *(const floatx4*)wp;
      floatx4 vb = *(const floatx4*)(wp + C);
#pragma unroll
      for (int i = 0; i < 4; ++i) *(unsigned*)&Bs[4 * nq + i][2 * kp] = pack2(va[i], vb[i]);
    }
    __syncthreads();
    half8v a0 = *(const half8v*)&As[w * 32 + mn][quad * 8];
    half8v a1 = *(const half8v*)&As[w * 32 + 16 + mn][quad * 8];
#pragma unroll
    for (int ni = 0; ni < 4; ++ni) {
      half8v bf = *(const half8v*)&Bs[ni * 16 + mn][quad * 8];
      acc[0][ni] = __builtin_amdgcn_mfma_f32_16x16x32_f16(a0, bf, acc[0][ni], 0, 0, 0);
      acc[1][ni] = __builtin_amdgcn_mfma_f32_16x16x32_f16(a1, bf, acc[1][ni], 0, 0, 0);
    }
    __syncthreads();   // also protects As/Bs before Cs aliasing overwrite
  }

  // epilogue: bias add into Cs, then transposed coalesced store
#pragma unroll
  for (int mi = 0; mi < 2; ++mi)
#pragma unroll
    for (int r = 0; r < 4; ++r)
#pragma unroll
      for (int ni = 0; ni < 4; ++ni)
        Cs[w * 32 + mi * 16 + quad * 4 + r][ni * 16 + mn] =
            acc[mi][ni][r] + bias[n0 + ni * 16 + mn];
  __syncthreads();
#pragma unroll
  for (int u = 0; u < 32; ++u) {
    int e = u * 256 + tid;            // 8192 elems: 128 m x 64 n
    int ml = e & 127, cl = e >> 7;
    int m = m0 + ml;
    if (m < Mg) {
      int bb = m / RPB;
      int r = m - bb * RPB;
      Yt[((size_t)bb * C + n0 + cl) * RPB + r] = Cs[ml][cl];
    }
  }
}

// ---------------- fold (gather form), group-local ----------------
__global__ __launch_bounds__(256) void fold_kernel(const float* __restrict__ Yt,
                                                   float* __restrict__ out,
                                                   int k_, int s_, int p_, int H_,
                                                   int toff, int total) {
  int idx = blockIdx.x * 256 + threadIdx.x;
  if (idx >= total) return;
  int x = idx % H_;
  int y = (idx / H_) % H_;
  int c = (idx / (H_ * H_)) % C;
  int b = idx / (C * H_ * H_);
  int py = y + p_, px = x + p_;
  int ay = py - k_ + 1;
  int wy_lo = ay <= 0 ? 0 : (ay + s_ - 1) / s_;
  int wy_hi = min(19, py / s_);
  int ax = px - k_ + 1;
  int wx_lo = ax <= 0 ? 0 : (ax + s_ - 1) / s_;
  int wx_hi = min(19, px / s_);
  const float* base = Yt + ((size_t)b * C + c) * RPB;
  float acc = 0.f;
  for (int wy = wy_lo; wy <= wy_hi; ++wy) {
    int tyy = py - wy * s_;
    for (int wx = wx_lo; wx <= wx_hi; ++wx) {
      int txx = px - wx * s_;
      acc += base[(wy * 20 + wx) * NT + toff + tyy * k_ + txx];
    }
  }
  out[idx] = acc;
}

} // namespace

extern "C" void kernel_launch(void* const* d_in, const int* in_sizes, int n_in,
                              void* d_out, int out_size, void* d_ws, size_t ws_size,
                              hipStream_t stream) {
  const float* x0    = (const float*)d_in[0];
  const float* x1    = (const float*)d_in[1];
  const float* x2    = (const float*)d_in[2];
  const float* wq0   = (const float*)d_in[3];
  const float* wq1   = (const float*)d_in[4];
  const float* wq2   = (const float*)d_in[5];
  const float* wproj = (const float*)d_in[6];
  const float* bproj = (const float*)d_in[7];
  const float* rpb   = (const float*)d_in[8];
  const float* ab    = (const float*)d_in[9];
  float* out = (float*)d_out;

  // pick largest batch-group size g in {8,4,2,1} that fits ws_size
  int g = 8;
  while (g > 1 && (4900 + (size_t)g * PB_F) * 4 > ws_size) g >>= 1;

  float* ws    = (float*)d_ws;
  float* posb  = ws;                         // 4900 floats
  float* qkv0g = ws + 4900;
  float* qkv1g = qkv0g + (size_t)g * 6400 * QKVN;
  float* qkv2g = qkv1g + (size_t)g * 1600 * QKVN;
  float* oatt  = qkv0g + (size_t)g * QKV_PB;
  float* yt    = qkv0g;                      // reuses dead qkv region after attention

  pos_kernel<<<(NH * NT * NT + 255) / 256, 256, 0, stream>>>(rpb, ab, posb);

  const size_t off1 = (size_t)B * C * 6400;
  const size_t off2 = off1 + (size_t)B * C * 1600;

  for (int b0 = 0; b0 < B; b0 += g) {
    const float* x0g = x0 + (size_t)b0 * C * 6400;
    const float* x1g = x1 + (size_t)b0 * C * 1600;
    const float* x2g = x2 + (size_t)b0 * C * 400;

    qkv_gemm<<<dim3((g * 6400 + 127) / 128, QKVN / 64), 256, 0, stream>>>(x0g, wq0, qkv0g, 6400, g * 6400, QKVN, 512);
    qkv_gemm<<<dim3((g * 1600 + 127) / 128, QKVN / 64), 256, 0, stream>>>(x1g, wq1, qkv1g, 1600, g * 1600, QKVN, 512);
    qkv_gemm<<<dim3((g *  400 + 127) / 128, QKVN / 64), 256, 0, stream>>>(x2g, wq2, qkv2g,  400, g *  400, QKVN, 512);

    attn_kernel<<<g * NH * NWIN, 64, 0, stream>>>(qkv0g, qkv1g, qkv2g, posb, oatt);

    proj_gemm<<<dim3((g * RPB + 127) / 128, C / 64), 256, 0, stream>>>(oatt, wproj, bproj, yt, g * RPB);

    const int tot0 = g * C * 6400;
    const int tot1 = g * C * 1600;
    const int tot2 = g * C * 400;
    fold_kernel<<<(tot0 + 255) / 256, 256, 0, stream>>>(yt, out + (size_t)b0 * C * 6400,        5, 4, 2, 80, 0,  tot0);
    fold_kernel<<<(tot1 + 255) / 256, 256, 0, stream>>>(yt, out + off1 + (size_t)b0 * C * 1600, 3, 2, 1, 40, 25, tot1);
    fold_kernel<<<(tot2 + 255) / 256, 256, 0, stream>>>(yt, out + off2 + (size_t)b0 * C * 400,  1, 1, 0, 20, 34, tot2);
  }
}

// Round 4
// 832.104 us; speedup vs baseline: 2.5195x; 1.2756x over previous
//
#include <hip/hip_runtime.h>
#include <math.h>

namespace {

typedef _Float16 half8v __attribute__((ext_vector_type(8)));
typedef _Float16 half4v __attribute__((ext_vector_type(4)));
typedef float    floatx4 __attribute__((ext_vector_type(4)));

constexpr int B   = 8;
constexpr int C   = 256;
constexpr int NH  = 4;
constexpr int HD  = 64;
constexpr int NWIN = 400;   // 20x20 windows per level
constexpr int NT  = 35;     // 25 + 9 + 1 tokens per window
constexpr int QKVN = 768;
constexpr int RPB = NWIN * NT;  // 14,000 token-rows per batch

// per-batch byte counts for workspace
constexpr size_t QKV_B  = (size_t)8400 * QKVN * 2;   // 12,902,400  (f16)
constexpr size_t OATT_B = (size_t)RPB * C * 2;       //  7,168,000  (f16)
constexpr size_t YT_B   = (size_t)RPB * C * 4;       // 14,336,000  (f32)
constexpr size_t PB_B   = QKV_B + OATT_B + YT_B;     // 34,406,400
constexpr size_t POS_B  = 19712;                     // 4900 f32, padded

__device__ inline unsigned pack2(float a, float b) {
  union { _Float16 h[2]; unsigned u; } x;
  x.h[0] = (_Float16)a; x.h[1] = (_Float16)b;
  return x.u;
}

// ---------------- pos table ----------------
__device__ inline void token_coord(int j, double& cy, double& cx) {
  if (j < 25)      { int ty = j / 5,  tx = j % 5;  cy = (double)(ty - 2); cx = (double)(tx - 2); }
  else if (j < 34) { int t = j - 25; int ty = t / 3, tx = t % 3;
                     cy = (double)(ty - 1) * (5.0 / 3.0); cx = (double)(tx - 1) * (5.0 / 3.0); }
  else             { cy = 0.0; cx = 0.0; }
}

__global__ void pos_kernel(const float* __restrict__ rpb, const float* __restrict__ ab,
                           float* __restrict__ pos) {
  int p = blockIdx.x * blockDim.x + threadIdx.x;
  if (p >= NH * NT * NT) return;
  int j = p % NT, i = (p / NT) % NT, h = p / (NT * NT);
  double cyi, cxi, cyj, cxj;
  token_coord(i, cyi, cxi);
  token_coord(j, cyj, cxj);
  float fidx = (float)(((cyi - cyj) + 4.0) * 9.0 + ((cxi - cxj) + 4.0));
  int fl = min(max((int)floorf(fidx), 0), 80);
  int ce = min(max((int)ceilf(fidx), 0), 80);
  float w = fidx - (float)fl;
  float pv = (1.0f - w) * rpb[fl * NH + h] + w * rpb[ce * NH + h];
  int li = (i < 25) ? 0 : ((i < 34) ? 1 : 2);
  pos[p] = pv + ab[li * NH + h];
}

// ---------------- QKV GEMM (f16 MFMA): Y[m, 768](f16) = X[b(m), :, pix(m)]^T @ W ----------------
// Epilogue: L2-normalize each output row over this 64-wide tile when n0 < normN (q,k sections).
__global__ __launch_bounds__(256) void qkv_gemm(const float* __restrict__ X,
                                                const float* __restrict__ W,
                                                _Float16* __restrict__ Y,
                                                int HW, int Mg, int normN) {
  __shared__ _Float16 As[128][40];   // row 80B, 16B-aligned frag reads
  __shared__ _Float16 Bs[64][40];
  const int tid  = threadIdx.x;
  const int m0   = blockIdx.x * 128;
  const int n0   = blockIdx.y * 64;
  const int w    = tid >> 6;
  const int lane = tid & 63;
  const int quad = lane >> 4;
  const int mn   = lane & 15;

  floatx4 acc[2][4] = {};
  for (int k0 = 0; k0 < C; k0 += 32) {
    // stage A: transpose (column-major global -> row-major LDS), f16x2 packed writes
#pragma unroll
    for (int u = 0; u < 2; ++u) {
      int unit = u * 256 + tid;        // 512 units: 32 m-quads x 16 k-pairs
      int mq = unit & 31, kp = unit >> 5;
      int mb = 4 * mq;
      int gm = m0 + mb;
      if (gm + 3 < Mg) {
        int bb = gm / HW; int pix = gm - bb * HW;
        const float* xp = X + ((size_t)bb * C + (k0 + 2 * kp)) * HW + pix;
        floatx4 va = *(const floatx4*)xp;
        floatx4 vb = *(const floatx4*)(xp + HW);
#pragma unroll
        for (int i = 0; i < 4; ++i) *(unsigned*)&As[mb + i][2 * kp] = pack2(va[i], vb[i]);
      } else {
#pragma unroll
        for (int i = 0; i < 4; ++i) {
          int g = min(gm + i, Mg - 1);
          int bb = g / HW; int pix = g - bb * HW;
          const float* xp = X + ((size_t)bb * C + (k0 + 2 * kp)) * HW + pix;
          *(unsigned*)&As[mb + i][2 * kp] = pack2(xp[0], xp[HW]);
        }
      }
    }
    // stage B: W row-major (K x 768)
    {
      int nq = tid & 15, kp = tid >> 4;
      const float* wp = W + (size_t)(k0 + 2 * kp) * QKVN + n0 + 4 * nq;
      floatx4 va = *(const floatx4*)wp;
      floatx4 vb = *(const floatx4*)(wp + QKVN);
#pragma unroll
      for (int i = 0; i < 4; ++i) *(unsigned*)&Bs[4 * nq + i][2 * kp] = pack2(va[i], vb[i]);
    }
    __syncthreads();
    half8v a0 = *(const half8v*)&As[w * 32 + mn][quad * 8];
    half8v a1 = *(const half8v*)&As[w * 32 + 16 + mn][quad * 8];
#pragma unroll
    for (int ni = 0; ni < 4; ++ni) {
      half8v bf = *(const half8v*)&Bs[ni * 16 + mn][quad * 8];
      acc[0][ni] = __builtin_amdgcn_mfma_f32_16x16x32_f16(a0, bf, acc[0][ni], 0, 0, 0);
      acc[1][ni] = __builtin_amdgcn_mfma_f32_16x16x32_f16(a1, bf, acc[1][ni], 0, 0, 0);
    }
    __syncthreads();
  }

  // epilogue: per-row L2 norm over the 64 cols of this tile (q,k head sections only)
  const bool do_norm = (n0 < normN);
#pragma unroll
  for (int mi = 0; mi < 2; ++mi) {
#pragma unroll
    for (int r = 0; r < 4; ++r) {
      float ss = 0.f;
#pragma unroll
      for (int ni = 0; ni < 4; ++ni) { float vv = acc[mi][ni][r]; ss += vv * vv; }
      ss += __shfl_xor(ss, 1);
      ss += __shfl_xor(ss, 2);
      ss += __shfl_xor(ss, 4);
      ss += __shfl_xor(ss, 8);
      float scale = do_norm ? (1.f / fmaxf(sqrtf(ss), 1e-12f)) : 1.f;
      int row = m0 + w * 32 + mi * 16 + quad * 4 + r;
      if (row < Mg) {
#pragma unroll
        for (int ni = 0; ni < 4; ++ni)
          Y[(size_t)row * QKVN + n0 + ni * 16 + mn] = (_Float16)(acc[mi][ni][r] * scale);
      }
    }
  }
}

// ---------------- attention: one wave per (b_local, h, w), pre-normalized q,k; f16 in/out ----------------
__global__ __launch_bounds__(64) void attn_kernel(const _Float16* __restrict__ qkv0,
                                                  const _Float16* __restrict__ qkv1,
                                                  const _Float16* __restrict__ qkv2,
                                                  const float* __restrict__ pos,
                                                  _Float16* __restrict__ O) {
  const int blk = blockIdx.x;               // ((b*NH + h)*NWIN + w)
  const int w = blk % NWIN;
  const int h = (blk / NWIN) % NH;
  const int b = blk / (NWIN * NH);
  const int wy = w / 20, wx = w % 20;
  const int lane = threadIdx.x;             // 0..63 = d

  __shared__ _Float16 qs[NT][72];   // 144B rows, 16B-aligned
  __shared__ _Float16 ks[NT][72];
  __shared__ float sc[NT][36];

  float vreg[36];
  vreg[35] = 0.f;

  // gather q/k (normalized, f16) to LDS, v to registers (zeros for padding tokens)
  for (int j = 0; j < NT; ++j) {
    int k_, s_, p_, Hl, t;
    const _Float16* base;
    if (j < 25)      { k_ = 5; s_ = 4; p_ = 2; Hl = 80; t = j;      base = qkv0; }
    else if (j < 34) { k_ = 3; s_ = 2; p_ = 1; Hl = 40; t = j - 25; base = qkv1; }
    else             { k_ = 1; s_ = 1; p_ = 0; Hl = 20; t = 0;      base = qkv2; }
    int tyy = t / k_, txx = t % k_;
    int y = wy * s_ + tyy - p_;
    int x = wx * s_ + txx - p_;
    _Float16 qv = (_Float16)0.f, kv = (_Float16)0.f;
    float vv = 0.f;
    if ((unsigned)y < (unsigned)Hl && (unsigned)x < (unsigned)Hl) {
      size_t rb = ((size_t)b * Hl * Hl + (size_t)y * Hl + x) * QKVN + h * HD + lane;
      qv = base[rb];
      kv = base[rb + 256];
      vv = (float)base[rb + 512];
    }
    qs[j][lane] = qv; ks[j][lane] = kv; vreg[j] = vv;
  }
  __syncthreads();

  // scores (half8 LDS reads, fp32 accumulate)
  for (int p = lane; p < NT * NT; p += 64) {
    int i = p / NT, j = p - i * NT;
    float acc = 0.f;
#pragma unroll
    for (int d = 0; d < HD; d += 8) {
      half8v q8 = *(const half8v*)&qs[i][d];
      half8v k8 = *(const half8v*)&ks[j][d];
#pragma unroll
      for (int t = 0; t < 8; ++t) acc += (float)q8[t] * (float)k8[t];
    }
    sc[i][j] = acc + pos[(h * NT + i) * NT + j];
  }
  __syncthreads();

  // softmax over j (writes sc[i][35] = 0 so PV can use float4)
  for (int i = 0; i < NT; ++i) {
    float val = (lane < NT) ? sc[i][lane] : -INFINITY;
    float m = val;
#pragma unroll
    for (int off = 32; off; off >>= 1) m = fmaxf(m, __shfl_xor(m, off));
    float e = (lane < NT) ? expf(val - m) : 0.f;
    float s = e;
#pragma unroll
    for (int off = 32; off; off >>= 1) s += __shfl_xor(s, off);
    if (lane < 36) sc[i][lane] = (lane < NT) ? (e / s) : 0.f;
  }
  __syncthreads();

  // PV with v in registers; sc reads are same-address broadcasts (conflict-free)
  for (int i = 0; i < NT; ++i) {
    float acc = 0.f;
#pragma unroll
    for (int j4 = 0; j4 < 9; ++j4) {
      floatx4 p4 = *(const floatx4*)&sc[i][4 * j4];
      acc += p4[0] * vreg[4 * j4] + p4[1] * vreg[4 * j4 + 1]
           + p4[2] * vreg[4 * j4 + 2] + p4[3] * vreg[4 * j4 + 3];
    }
    O[((size_t)(b * NWIN + w) * NT + i) * C + h * HD + lane] = (_Float16)acc;
  }
}

// ---------------- proj GEMM (f16 MFMA) + bias, transposed store Yt[(b*C+c)*RPB + w*35+j] ----------------
__global__ __launch_bounds__(256) void proj_gemm(const _Float16* __restrict__ A,  // (Mg, 256) f16 row-major
                                                 const float* __restrict__ W,     // (256, 256) row-major
                                                 const float* __restrict__ bias,
                                                 float* __restrict__ Yt, int Mg) {
  __shared__ __align__(16) char smem[128 * 69 * 4];   // max(As+Bs = 15360, Cs = 35328)
  _Float16 (*As)[40] = (_Float16(*)[40])smem;
  _Float16 (*Bs)[40] = (_Float16(*)[40])(smem + 128 * 40 * 2);
  float    (*Cs)[69] = (float(*)[69])smem;

  const int tid  = threadIdx.x;
  const int m0   = blockIdx.x * 128;
  const int n0   = blockIdx.y * 64;
  const int w    = tid >> 6;
  const int lane = tid & 63;
  const int quad = lane >> 4;
  const int mn   = lane & 15;

  floatx4 acc[2][4] = {};
  for (int k0 = 0; k0 < C; k0 += 32) {
    // stage A (f16 row-major): straight half8 copies
#pragma unroll
    for (int u = 0; u < 2; ++u) {
      int e = u * 256 + tid;           // 512 units: 128 m x 4 k-octs
      int m = e >> 2, k8 = e & 3;
      int row = min(m0 + m, Mg - 1);
      half8v va = *(const half8v*)&A[(size_t)row * C + k0 + 8 * k8];
      *(half8v*)&As[m][8 * k8] = va;
    }
    // stage B (f32 -> f16)
    {
      int nq = tid & 15, kp = tid >> 4;
      const float* wp = W + (size_t)(k0 + 2 * kp) * C + n0 + 4 * nq;
      floatx4 va = *(const floatx4*)wp;
      floatx4 vb = *(const floatx4*)(wp + C);
#pragma unroll
      for (int i = 0; i < 4; ++i) *(unsigned*)&Bs[4 * nq + i][2 * kp] = pack2(va[i], vb[i]);
    }
    __syncthreads();
    half8v a0 = *(const half8v*)&As[w * 32 + mn][quad * 8];
    half8v a1 = *(const half8v*)&As[w * 32 + 16 + mn][quad * 8];
#pragma unroll
    for (int ni = 0; ni < 4; ++ni) {
      half8v bf = *(const half8v*)&Bs[ni * 16 + mn][quad * 8];
      acc[0][ni] = __builtin_amdgcn_mfma_f32_16x16x32_f16(a0, bf, acc[0][ni], 0, 0, 0);
      acc[1][ni] = __builtin_amdgcn_mfma_f32_16x16x32_f16(a1, bf, acc[1][ni], 0, 0, 0);
    }
    __syncthreads();   // also protects As/Bs before Cs aliasing overwrite
  }

  // epilogue: bias add into Cs, then transposed coalesced store
#pragma unroll
  for (int mi = 0; mi < 2; ++mi)
#pragma unroll
    for (int r = 0; r < 4; ++r)
#pragma unroll
      for (int ni = 0; ni < 4; ++ni)
        Cs[w * 32 + mi * 16 + quad * 4 + r][ni * 16 + mn] =
            acc[mi][ni][r] + bias[n0 + ni * 16 + mn];
  __syncthreads();
#pragma unroll
  for (int u = 0; u < 32; ++u) {
    int e = u * 256 + tid;            // 8192 elems: 128 m x 64 n
    int ml = e & 127, cl = e >> 7;
    int m = m0 + ml;
    if (m < Mg) {
      int bb = m / RPB;
      int r = m - bb * RPB;
      Yt[((size_t)bb * C + n0 + cl) * RPB + r] = Cs[ml][cl];
    }
  }
}

// ---------------- fold (gather form), group-local ----------------
__global__ __launch_bounds__(256) void fold_kernel(const float* __restrict__ Yt,
                                                   float* __restrict__ out,
                                                   int k_, int s_, int p_, int H_,
                                                   int toff, int total) {
  int idx = blockIdx.x * 256 + threadIdx.x;
  if (idx >= total) return;
  int x = idx % H_;
  int y = (idx / H_) % H_;
  int c = (idx / (H_ * H_)) % C;
  int b = idx / (C * H_ * H_);
  int py = y + p_, px = x + p_;
  int ay = py - k_ + 1;
  int wy_lo = ay <= 0 ? 0 : (ay + s_ - 1) / s_;
  int wy_hi = min(19, py / s_);
  int ax = px - k_ + 1;
  int wx_lo = ax <= 0 ? 0 : (ax + s_ - 1) / s_;
  int wx_hi = min(19, px / s_);
  const float* base = Yt + ((size_t)b * C + c) * RPB;
  float acc = 0.f;
  for (int wy = wy_lo; wy <= wy_hi; ++wy) {
    int tyy = py - wy * s_;
    for (int wx = wx_lo; wx <= wx_hi; ++wx) {
      int txx = px - wx * s_;
      acc += base[(wy * 20 + wx) * NT + toff + tyy * k_ + txx];
    }
  }
  out[idx] = acc;
}

} // namespace

extern "C" void kernel_launch(void* const* d_in, const int* in_sizes, int n_in,
                              void* d_out, int out_size, void* d_ws, size_t ws_size,
                              hipStream_t stream) {
  const float* x0    = (const float*)d_in[0];
  const float* x1    = (const float*)d_in[1];
  const float* x2    = (const float*)d_in[2];
  const float* wq0   = (const float*)d_in[3];
  const float* wq1   = (const float*)d_in[4];
  const float* wq2   = (const float*)d_in[5];
  const float* wproj = (const float*)d_in[6];
  const float* bproj = (const float*)d_in[7];
  const float* rpb   = (const float*)d_in[8];
  const float* ab    = (const float*)d_in[9];
  float* out = (float*)d_out;

  // pick largest batch-group size g in {8,4,2,1} that fits ws_size
  int g = 8;
  while (g > 1 && POS_B + (size_t)g * PB_B > ws_size) g >>= 1;

  char* ws = (char*)d_ws;
  float*    posb  = (float*)ws;
  _Float16* qkv0g = (_Float16*)(ws + POS_B);
  _Float16* qkv1g = qkv0g + (size_t)g * 6400 * QKVN;
  _Float16* qkv2g = qkv1g + (size_t)g * 1600 * QKVN;
  _Float16* oatt  = qkv2g + (size_t)g *  400 * QKVN;
  float*    yt    = (float*)(ws + POS_B + (size_t)g * (QKV_B + OATT_B));

  pos_kernel<<<(NH * NT * NT + 255) / 256, 256, 0, stream>>>(rpb, ab, posb);

  const size_t off1 = (size_t)B * C * 6400;
  const size_t off2 = off1 + (size_t)B * C * 1600;

  for (int b0 = 0; b0 < B; b0 += g) {
    const float* x0g = x0 + (size_t)b0 * C * 6400;
    const float* x1g = x1 + (size_t)b0 * C * 1600;
    const float* x2g = x2 + (size_t)b0 * C * 400;

    qkv_gemm<<<dim3((g * 6400 + 127) / 128, QKVN / 64), 256, 0, stream>>>(x0g, wq0, qkv0g, 6400, g * 6400, 512);
    qkv_gemm<<<dim3((g * 1600 + 127) / 128, QKVN / 64), 256, 0, stream>>>(x1g, wq1, qkv1g, 1600, g * 1600, 512);
    qkv_gemm<<<dim3((g *  400 + 127) / 128, QKVN / 64), 256, 0, stream>>>(x2g, wq2, qkv2g,  400, g *  400, 512);

    attn_kernel<<<g * NH * NWIN, 64, 0, stream>>>(qkv0g, qkv1g, qkv2g, posb, oatt);

    proj_gemm<<<dim3((g * RPB + 127) / 128, C / 64), 256, 0, stream>>>(oatt, wproj, bproj, yt, g * RPB);

    const int tot0 = g * C * 6400;
    const int tot1 = g * C * 1600;
    const int tot2 = g * C * 400;
    fold_kernel<<<(tot0 + 255) / 256, 256, 0, stream>>>(yt, out + (size_t)b0 * C * 6400,        5, 4, 2, 80, 0,  tot0);
    fold_kernel<<<(tot1 + 255) / 256, 256, 0, stream>>>(yt, out + off1 + (size_t)b0 * C * 1600, 3, 2, 1, 40, 25, tot1);
    fold_kernel<<<(tot2 + 255) / 256, 256, 0, stream>>>(yt, out + off2 + (size_t)b0 * C * 400,  1, 1, 0, 20, 34, tot2);
  }
}

// Round 5
// 739.850 us; speedup vs baseline: 2.8336x; 1.1247x over previous
//
#include <hip/hip_runtime.h>
#include <math.h>

namespace {

typedef _Float16 half8v __attribute__((ext_vector_type(8)));
typedef float    floatx4 __attribute__((ext_vector_type(4)));

constexpr int B   = 8;
constexpr int C   = 256;
constexpr int NH  = 4;
constexpr int HD  = 64;
constexpr int NWIN = 400;   // 20x20 windows per level
constexpr int NT  = 35;     // 25 + 9 + 1 tokens per window
constexpr int QKVN = 768;
constexpr int RPB = NWIN * NT;  // 14,000 token-rows per batch

// per-batch byte counts for workspace
constexpr size_t QKV_B  = (size_t)8400 * QKVN * 2;   // 12,902,400  (f16)
constexpr size_t OATT_B = (size_t)RPB * C * 2;       //  7,168,000  (f16)
constexpr size_t YT_B   = (size_t)RPB * C * 4;       // 14,336,000  (f32)
constexpr size_t PB_B   = QKV_B + OATT_B + YT_B;     // 34,406,400
constexpr size_t POS_B  = 19712;                     // 4900 f32, padded

__device__ inline unsigned pack2(float a, float b) {
  union { _Float16 h[2]; unsigned u; } x;
  x.h[0] = (_Float16)a; x.h[1] = (_Float16)b;
  return x.u;
}

// ---------------- pos table ----------------
__device__ inline void token_coord(int j, double& cy, double& cx) {
  if (j < 25)      { int ty = j / 5,  tx = j % 5;  cy = (double)(ty - 2); cx = (double)(tx - 2); }
  else if (j < 34) { int t = j - 25; int ty = t / 3, tx = t % 3;
                     cy = (double)(ty - 1) * (5.0 / 3.0); cx = (double)(tx - 1) * (5.0 / 3.0); }
  else             { cy = 0.0; cx = 0.0; }
}

__global__ void pos_kernel(const float* __restrict__ rpb, const float* __restrict__ ab,
                           float* __restrict__ pos) {
  int p = blockIdx.x * blockDim.x + threadIdx.x;
  if (p >= NH * NT * NT) return;
  int j = p % NT, i = (p / NT) % NT, h = p / (NT * NT);
  double cyi, cxi, cyj, cxj;
  token_coord(i, cyi, cxi);
  token_coord(j, cyj, cxj);
  float fidx = (float)(((cyi - cyj) + 4.0) * 9.0 + ((cxi - cxj) + 4.0));
  int fl = min(max((int)floorf(fidx), 0), 80);
  int ce = min(max((int)ceilf(fidx), 0), 80);
  float w = fidx - (float)fl;
  float pv = (1.0f - w) * rpb[fl * NH + h] + w * rpb[ce * NH + h];
  int li = (i < 25) ? 0 : ((i < 34) ? 1 : 2);
  pos[p] = pv + ab[li * NH + h];
}

// ---------------- QKV GEMM (f16 MFMA, 128x128 tile): Y[m, 768](f16) = X^T @ W ----------------
// Epilogue: L2-normalize each output row per 64-col head section when n0 < normN (q,k).
__global__ __launch_bounds__(256) void qkv_gemm(const float* __restrict__ X,
                                                const float* __restrict__ W,
                                                _Float16* __restrict__ Y,
                                                int HW, int Mg, int normN) {
  __shared__ _Float16 As[128][40];   // row 80B, 16B-aligned frag reads
  __shared__ _Float16 Bs[128][40];
  const int tid  = threadIdx.x;
  const int m0   = blockIdx.x * 128;
  const int n0   = blockIdx.y * 128;
  const int w    = tid >> 6;
  const int lane = tid & 63;
  const int quad = lane >> 4;
  const int mn   = lane & 15;

  floatx4 acc[2][8] = {};
  for (int k0 = 0; k0 < C; k0 += 32) {
    // stage A: transpose (column-major global -> row-major LDS), f16x2 packed writes
#pragma unroll
    for (int u = 0; u < 2; ++u) {
      int unit = u * 256 + tid;        // 512 units: 32 m-quads x 16 k-pairs
      int mq = unit & 31, kp = unit >> 5;
      int mb = 4 * mq;
      int gm = m0 + mb;
      if (gm + 3 < Mg) {
        int bb = gm / HW; int pix = gm - bb * HW;
        const float* xp = X + ((size_t)bb * C + (k0 + 2 * kp)) * HW + pix;
        floatx4 va = *(const floatx4*)xp;
        floatx4 vb = *(const floatx4*)(xp + HW);
#pragma unroll
        for (int i = 0; i < 4; ++i) *(unsigned*)&As[mb + i][2 * kp] = pack2(va[i], vb[i]);
      } else {
#pragma unroll
        for (int i = 0; i < 4; ++i) {
          int g = min(gm + i, Mg - 1);
          int bb = g / HW; int pix = g - bb * HW;
          const float* xp = X + ((size_t)bb * C + (k0 + 2 * kp)) * HW + pix;
          *(unsigned*)&As[mb + i][2 * kp] = pack2(xp[0], xp[HW]);
        }
      }
    }
    // stage B: W row-major (K x 768), 128 cols
#pragma unroll
    for (int u = 0; u < 2; ++u) {
      int e = u * 256 + tid;           // 512 units: 32 n-quads x 16 k-pairs
      int nq = e & 31, kp = e >> 5;
      const float* wp = W + (size_t)(k0 + 2 * kp) * QKVN + n0 + 4 * nq;
      floatx4 va = *(const floatx4*)wp;
      floatx4 vb = *(const floatx4*)(wp + QKVN);
#pragma unroll
      for (int i = 0; i < 4; ++i) *(unsigned*)&Bs[4 * nq + i][2 * kp] = pack2(va[i], vb[i]);
    }
    __syncthreads();
    half8v a0 = *(const half8v*)&As[w * 32 + mn][quad * 8];
    half8v a1 = *(const half8v*)&As[w * 32 + 16 + mn][quad * 8];
#pragma unroll
    for (int ni = 0; ni < 8; ++ni) {
      half8v bf = *(const half8v*)&Bs[ni * 16 + mn][quad * 8];
      acc[0][ni] = __builtin_amdgcn_mfma_f32_16x16x32_f16(a0, bf, acc[0][ni], 0, 0, 0);
      acc[1][ni] = __builtin_amdgcn_mfma_f32_16x16x32_f16(a1, bf, acc[1][ni], 0, 0, 0);
    }
    __syncthreads();
  }

  // epilogue: per-row L2 norm per 64-col head section (two sections per 128-tile)
  const bool do_norm = (n0 < normN);
#pragma unroll
  for (int mi = 0; mi < 2; ++mi) {
#pragma unroll
    for (int r = 0; r < 4; ++r) {
      float s0 = 0.f, s1 = 0.f;
#pragma unroll
      for (int ni = 0; ni < 4; ++ni) { float vv = acc[mi][ni][r]; s0 += vv * vv; }
#pragma unroll
      for (int ni = 4; ni < 8; ++ni) { float vv = acc[mi][ni][r]; s1 += vv * vv; }
      s0 += __shfl_xor(s0, 1); s1 += __shfl_xor(s1, 1);
      s0 += __shfl_xor(s0, 2); s1 += __shfl_xor(s1, 2);
      s0 += __shfl_xor(s0, 4); s1 += __shfl_xor(s1, 4);
      s0 += __shfl_xor(s0, 8); s1 += __shfl_xor(s1, 8);
      float sc0 = do_norm ? (1.f / fmaxf(sqrtf(s0), 1e-12f)) : 1.f;
      float sc1 = do_norm ? (1.f / fmaxf(sqrtf(s1), 1e-12f)) : 1.f;
      int row = m0 + w * 32 + mi * 16 + quad * 4 + r;
      if (row < Mg) {
#pragma unroll
        for (int ni = 0; ni < 8; ++ni)
          Y[(size_t)row * QKVN + n0 + ni * 16 + mn] =
              (_Float16)(acc[mi][ni][r] * (ni < 4 ? sc0 : sc1));
      }
    }
  }
}

// ---------------- attention: 4 waves per (b_local, h, w); f16 in/out ----------------
__global__ __launch_bounds__(256) void attn_kernel(const _Float16* __restrict__ qkv0,
                                                   const _Float16* __restrict__ qkv1,
                                                   const _Float16* __restrict__ qkv2,
                                                   const float* __restrict__ pos,
                                                   _Float16* __restrict__ O) {
  const int blk = blockIdx.x;               // ((b*NH + h)*NWIN + w)
  const int w = blk % NWIN;
  const int h = (blk / NWIN) % NH;
  const int b = blk / (NWIN * NH);
  const int wy = w / 20, wx = w % 20;
  const int tid  = threadIdx.x;
  const int wv   = tid >> 6;                // wave 0..3
  const int lane = tid & 63;                // d

  __shared__ _Float16 qs[NT][72];   // 144B rows, 16B-aligned
  __shared__ _Float16 ks[NT][72];
  __shared__ _Float16 vs[NT][72];
  __shared__ float sc[NT][36];

  // gather q/k/v (normalized q,k; zeros for padding tokens), tokens split by wave
  for (int j = wv; j < NT; j += 4) {
    int k_, s_, p_, Hl, t;
    const _Float16* base;
    if (j < 25)      { k_ = 5; s_ = 4; p_ = 2; Hl = 80; t = j;      base = qkv0; }
    else if (j < 34) { k_ = 3; s_ = 2; p_ = 1; Hl = 40; t = j - 25; base = qkv1; }
    else             { k_ = 1; s_ = 1; p_ = 0; Hl = 20; t = 0;      base = qkv2; }
    int tyy = t / k_, txx = t % k_;
    int y = wy * s_ + tyy - p_;
    int x = wx * s_ + txx - p_;
    _Float16 qv = (_Float16)0.f, kv = (_Float16)0.f, vv = (_Float16)0.f;
    if ((unsigned)y < (unsigned)Hl && (unsigned)x < (unsigned)Hl) {
      size_t rb = ((size_t)b * Hl * Hl + (size_t)y * Hl + x) * QKVN + h * HD + lane;
      qv = base[rb];
      kv = base[rb + 256];
      vv = base[rb + 512];
    }
    qs[j][lane] = qv; ks[j][lane] = kv; vs[j][lane] = vv;
  }
  __syncthreads();

  // scores (half8 LDS reads, fp32 accumulate), 1225 pairs over 256 threads
  for (int p = tid; p < NT * NT; p += 256) {
    int i = p / NT, j = p - i * NT;
    float acc = 0.f;
#pragma unroll
    for (int d = 0; d < HD; d += 8) {
      half8v q8 = *(const half8v*)&qs[i][d];
      half8v k8 = *(const half8v*)&ks[j][d];
#pragma unroll
      for (int t = 0; t < 8; ++t) acc += (float)q8[t] * (float)k8[t];
    }
    sc[i][j] = acc + pos[(h * NT + i) * NT + j];
  }
  __syncthreads();

  // softmax over j, rows split by wave (writes sc[i][35] = 0 so PV can use float4)
  for (int i = wv; i < NT; i += 4) {
    float val = (lane < NT) ? sc[i][lane] : -INFINITY;
    float m = val;
#pragma unroll
    for (int off = 32; off; off >>= 1) m = fmaxf(m, __shfl_xor(m, off));
    float e = (lane < NT) ? expf(val - m) : 0.f;
    float s = e;
#pragma unroll
    for (int off = 32; off; off >>= 1) s += __shfl_xor(s, off);
    if (lane < 36) sc[i][lane] = (lane < NT) ? (e / s) : 0.f;
  }
  __syncthreads();

  // PV: per-wave v registers, rows split by wave; sc reads are broadcasts
  float vreg[36];
  vreg[35] = 0.f;
#pragma unroll
  for (int j = 0; j < NT; ++j) vreg[j] = (float)vs[j][lane];
  for (int i = wv; i < NT; i += 4) {
    float acc = 0.f;
#pragma unroll
    for (int j4 = 0; j4 < 9; ++j4) {
      floatx4 p4 = *(const floatx4*)&sc[i][4 * j4];
      acc += p4[0] * vreg[4 * j4] + p4[1] * vreg[4 * j4 + 1]
           + p4[2] * vreg[4 * j4 + 2] + p4[3] * vreg[4 * j4 + 3];
    }
    O[((size_t)(b * NWIN + w) * NT + i) * C + h * HD + lane] = (_Float16)acc;
  }
}

// ---------------- proj GEMM (f16 MFMA) + bias, transposed store Yt[(b*C+c)*RPB + w*35+j] ----------------
__global__ __launch_bounds__(256) void proj_gemm(const _Float16* __restrict__ A,  // (Mg, 256) f16 row-major
                                                 const float* __restrict__ W,     // (256, 256) row-major
                                                 const float* __restrict__ bias,
                                                 float* __restrict__ Yt, int Mg) {
  __shared__ __align__(16) char smem[128 * 69 * 4];   // max(As+Bs = 15360, Cs = 35328)
  _Float16 (*As)[40] = (_Float16(*)[40])smem;
  _Float16 (*Bs)[40] = (_Float16(*)[40])(smem + 128 * 40 * 2);
  float    (*Cs)[69] = (float(*)[69])smem;

  const int tid  = threadIdx.x;
  const int m0   = blockIdx.x * 128;
  const int n0   = blockIdx.y * 64;
  const int w    = tid >> 6;
  const int lane = tid & 63;
  const int quad = lane >> 4;
  const int mn   = lane & 15;

  floatx4 acc[2][4] = {};
  for (int k0 = 0; k0 < C; k0 += 32) {
    // stage A (f16 row-major): straight half8 copies
#pragma unroll
    for (int u = 0; u < 2; ++u) {
      int e = u * 256 + tid;           // 512 units: 128 m x 4 k-octs
      int m = e >> 2, k8 = e & 3;
      int row = min(m0 + m, Mg - 1);
      half8v va = *(const half8v*)&A[(size_t)row * C + k0 + 8 * k8];
      *(half8v*)&As[m][8 * k8] = va;
    }
    // stage B (f32 -> f16)
    {
      int nq = tid & 15, kp = tid >> 4;
      const float* wp = W + (size_t)(k0 + 2 * kp) * C + n0 + 4 * nq;
      floatx4 va = *(const floatx4*)wp;
      floatx4 vb = *(const floatx4*)(wp + C);
#pragma unroll
      for (int i = 0; i < 4; ++i) *(unsigned*)&Bs[4 * nq + i][2 * kp] = pack2(va[i], vb[i]);
    }
    __syncthreads();
    half8v a0 = *(const half8v*)&As[w * 32 + mn][quad * 8];
    half8v a1 = *(const half8v*)&As[w * 32 + 16 + mn][quad * 8];
#pragma unroll
    for (int ni = 0; ni < 4; ++ni) {
      half8v bf = *(const half8v*)&Bs[ni * 16 + mn][quad * 8];
      acc[0][ni] = __builtin_amdgcn_mfma_f32_16x16x32_f16(a0, bf, acc[0][ni], 0, 0, 0);
      acc[1][ni] = __builtin_amdgcn_mfma_f32_16x16x32_f16(a1, bf, acc[1][ni], 0, 0, 0);
    }
    __syncthreads();   // also protects As/Bs before Cs aliasing overwrite
  }

  // epilogue: bias add into Cs, then transposed coalesced store
#pragma unroll
  for (int mi = 0; mi < 2; ++mi)
#pragma unroll
    for (int r = 0; r < 4; ++r)
#pragma unroll
      for (int ni = 0; ni < 4; ++ni)
        Cs[w * 32 + mi * 16 + quad * 4 + r][ni * 16 + mn] =
            acc[mi][ni][r] + bias[n0 + ni * 16 + mn];
  __syncthreads();
#pragma unroll
  for (int u = 0; u < 32; ++u) {
    int e = u * 256 + tid;            // 8192 elems: 128 m x 64 n
    int ml = e & 127, cl = e >> 7;
    int m = m0 + ml;
    if (m < Mg) {
      int bb = m / RPB;
      int r = m - bb * RPB;
      Yt[((size_t)bb * C + n0 + cl) * RPB + r] = Cs[ml][cl];
    }
  }
}

// ---------------- fold (gather form), group-local ----------------
__global__ __launch_bounds__(256) void fold_kernel(const float* __restrict__ Yt,
                                                   float* __restrict__ out,
                                                   int k_, int s_, int p_, int H_,
                                                   int toff, int total) {
  int idx = blockIdx.x * 256 + threadIdx.x;
  if (idx >= total) return;
  int x = idx % H_;
  int y = (idx / H_) % H_;
  int c = (idx / (H_ * H_)) % C;
  int b = idx / (C * H_ * H_);
  int py = y + p_, px = x + p_;
  int ay = py - k_ + 1;
  int wy_lo = ay <= 0 ? 0 : (ay + s_ - 1) / s_;
  int wy_hi = min(19, py / s_);
  int ax = px - k_ + 1;
  int wx_lo = ax <= 0 ? 0 : (ax + s_ - 1) / s_;
  int wx_hi = min(19, px / s_);
  const float* base = Yt + ((size_t)b * C + c) * RPB;
  float acc = 0.f;
  for (int wy = wy_lo; wy <= wy_hi; ++wy) {
    int tyy = py - wy * s_;
    for (int wx = wx_lo; wx <= wx_hi; ++wx) {
      int txx = px - wx * s_;
      acc += base[(wy * 20 + wx) * NT + toff + tyy * k_ + txx];
    }
  }
  out[idx] = acc;
}

} // namespace

extern "C" void kernel_launch(void* const* d_in, const int* in_sizes, int n_in,
                              void* d_out, int out_size, void* d_ws, size_t ws_size,
                              hipStream_t stream) {
  const float* x0    = (const float*)d_in[0];
  const float* x1    = (const float*)d_in[1];
  const float* x2    = (const float*)d_in[2];
  const float* wq0   = (const float*)d_in[3];
  const float* wq1   = (const float*)d_in[4];
  const float* wq2   = (const float*)d_in[5];
  const float* wproj = (const float*)d_in[6];
  const float* bproj = (const float*)d_in[7];
  const float* rpb   = (const float*)d_in[8];
  const float* ab    = (const float*)d_in[9];
  float* out = (float*)d_out;

  // pick largest batch-group size g in {8,4,2,1} that fits ws_size
  int g = 8;
  while (g > 1 && POS_B + (size_t)g * PB_B > ws_size) g >>= 1;

  char* ws = (char*)d_ws;
  float*    posb  = (float*)ws;
  _Float16* qkv0g = (_Float16*)(ws + POS_B);
  _Float16* qkv1g = qkv0g + (size_t)g * 6400 * QKVN;
  _Float16* qkv2g = qkv1g + (size_t)g * 1600 * QKVN;
  _Float16* oatt  = qkv2g + (size_t)g *  400 * QKVN;
  float*    yt    = (float*)(ws + POS_B + (size_t)g * (QKV_B + OATT_B));

  pos_kernel<<<(NH * NT * NT + 255) / 256, 256, 0, stream>>>(rpb, ab, posb);

  const size_t off1 = (size_t)B * C * 6400;
  const size_t off2 = off1 + (size_t)B * C * 1600;

  for (int b0 = 0; b0 < B; b0 += g) {
    const float* x0g = x0 + (size_t)b0 * C * 6400;
    const float* x1g = x1 + (size_t)b0 * C * 1600;
    const float* x2g = x2 + (size_t)b0 * C * 400;

    qkv_gemm<<<dim3((g * 6400 + 127) / 128, QKVN / 128), 256, 0, stream>>>(x0g, wq0, qkv0g, 6400, g * 6400, 512);
    qkv_gemm<<<dim3((g * 1600 + 127) / 128, QKVN / 128), 256, 0, stream>>>(x1g, wq1, qkv1g, 1600, g * 1600, 512);
    qkv_gemm<<<dim3((g *  400 + 127) / 128, QKVN / 128), 256, 0, stream>>>(x2g, wq2, qkv2g,  400, g *  400, 512);

    attn_kernel<<<g * NH * NWIN, 256, 0, stream>>>(qkv0g, qkv1g, qkv2g, posb, oatt);

    proj_gemm<<<dim3((g * RPB + 127) / 128, C / 64), 256, 0, stream>>>(oatt, wproj, bproj, yt, g * RPB);

    const int tot0 = g * C * 6400;
    const int tot1 = g * C * 1600;
    const int tot2 = g * C * 400;
    fold_kernel<<<(tot0 + 255) / 256, 256, 0, stream>>>(yt, out + (size_t)b0 * C * 6400,        5, 4, 2, 80, 0,  tot0);
    fold_kernel<<<(tot1 + 255) / 256, 256, 0, stream>>>(yt, out + off1 + (size_t)b0 * C * 1600, 3, 2, 1, 40, 25, tot1);
    fold_kernel<<<(tot2 + 255) / 256, 256, 0, stream>>>(yt, out + off2 + (size_t)b0 * C * 400,  1, 1, 0, 20, 34, tot2);
  }
}